// Round 1
// baseline (155.271 us; speedup 1.0000x reference)
//
#include <hip/hip_runtime.h>
#include <hip/hip_bf16.h>
#include <math.h>

typedef __bf16 bf16x8 __attribute__((ext_vector_type(8)));
typedef float  f32x4  __attribute__((ext_vector_type(4)));
typedef unsigned short ushort_t;

#define LDK 72   // padded LDS row for preconvert transpose only

// ws layout (bytes):
//   Kg  : [12][4096][64] bf16  (gathered, per-head)          @ 0        (6291456)
//   VgT : [12][64][4096] bf16  (gathered, transposed)        @ 6291456  (6291456)
//   l_acc: [4096*12] f32                                     @ 12582912 (196608)
#define KG_OFF  0
#define VGT_OFF 6291456
#define LACC_OFF 12582912

__device__ __forceinline__ int gather_pos(int gi, int group) {
    // gathered index gi (global) -> original sequence position
    const int lsl = 10 + group;           // log2(segment length)
    const int seg = gi >> lsl;
    const int j   = gi - (seg << lsl);
    return (seg << lsl) + group + ((j & 1023) << group);
}

// async 16B global->LDS (lane-linear LDS dest: base + lane*16)
__device__ __forceinline__ void gld_lds16(const ushort_t* g, __bf16* l) {
    __builtin_amdgcn_global_load_lds(
        (const __attribute__((address_space(1))) void*)g,
        (__attribute__((address_space(3))) void*)l, 16, 0, 0);
}

// ---------------- pre-convert kernel: fp32 -> bf16, gather + transpose ----------------
__global__ __launch_bounds__(256)
void preconvert_kernel(const float* __restrict__ K, const float* __restrict__ V,
                       ushort_t* __restrict__ Kg, ushort_t* __restrict__ VgT)
{
    const int HD = 768;
    int b = blockIdx.x;
    const int tid = threadIdx.x;
    if (b < 768) {
        // K part: Kg[h][gi][d]
        const int h = b % 12, gi0 = (b / 12) * 64;
        const int group = h >> 2;
        const int gi = gi0 + (tid >> 2);
        const int d0 = (tid & 3) << 4;
        const int pos = gather_pos(gi, group);
        const float* kp = K + (size_t)pos * HD + h * 64 + d0;
        float4 x0 = ((const float4*)kp)[0], x1 = ((const float4*)kp)[1];
        float4 x2 = ((const float4*)kp)[2], x3 = ((const float4*)kp)[3];
        bf16x8 w0, w1;
        w0[0]=(__bf16)x0.x; w0[1]=(__bf16)x0.y; w0[2]=(__bf16)x0.z; w0[3]=(__bf16)x0.w;
        w0[4]=(__bf16)x1.x; w0[5]=(__bf16)x1.y; w0[6]=(__bf16)x1.z; w0[7]=(__bf16)x1.w;
        w1[0]=(__bf16)x2.x; w1[1]=(__bf16)x2.y; w1[2]=(__bf16)x2.z; w1[3]=(__bf16)x2.w;
        w1[4]=(__bf16)x3.x; w1[5]=(__bf16)x3.y; w1[6]=(__bf16)x3.z; w1[7]=(__bf16)x3.w;
        ushort_t* out = Kg + ((size_t)(h * 4096 + gi)) * 64 + d0;
        *(bf16x8*)out = w0;
        *(bf16x8*)(out + 8) = w1;
    } else {
        // V part: VgT[h][d][gi] via LDS transpose
        b -= 768;
        const int h = b % 12, gi0 = (b / 12) * 64;
        const int group = h >> 2;
        __shared__ __align__(16) __bf16 Ts[64 * LDK];
        const int gil = tid >> 2;
        const int d0 = (tid & 3) << 4;
        const int pos = gather_pos(gi0 + gil, group);
        const float* vp = V + (size_t)pos * HD + h * 64 + d0;
        float4 x0 = ((const float4*)vp)[0], x1 = ((const float4*)vp)[1];
        float4 x2 = ((const float4*)vp)[2], x3 = ((const float4*)vp)[3];
        bf16x8 w0, w1;
        w0[0]=(__bf16)x0.x; w0[1]=(__bf16)x0.y; w0[2]=(__bf16)x0.z; w0[3]=(__bf16)x0.w;
        w0[4]=(__bf16)x1.x; w0[5]=(__bf16)x1.y; w0[6]=(__bf16)x1.z; w0[7]=(__bf16)x1.w;
        w1[0]=(__bf16)x2.x; w1[1]=(__bf16)x2.y; w1[2]=(__bf16)x2.z; w1[3]=(__bf16)x2.w;
        w1[4]=(__bf16)x3.x; w1[5]=(__bf16)x3.y; w1[6]=(__bf16)x3.z; w1[7]=(__bf16)x3.w;
        *(bf16x8*)&Ts[gil * LDK + d0]     = w0;
        *(bf16x8*)&Ts[gil * LDK + d0 + 8] = w1;
        __syncthreads();
        const int d = tid >> 2, c = tid & 3;
        bf16x8 o0, o1;
        #pragma unroll
        for (int i = 0; i < 8; ++i) {
            o0[i] = Ts[(c * 16 + i) * LDK + d];
            o1[i] = Ts[(c * 16 + 8 + i) * LDK + d];
        }
        ushort_t* out = VgT + ((size_t)(h * 64 + d)) * 4096 + gi0 + c * 16;
        *(bf16x8*)out = o0;
        *(bf16x8*)(out + 8) = o1;
    }
}

// ---------------- main attention kernel (split-K chunks of <=16 tiles) ----------------
// LDS: unpadded 128B rows + XOR-16B-block swizzle: element (row,col) lives at
//   row*64 + ((col>>3) ^ (row&7))*8 + (col&7)
// Staging via global_load_lds (lane-linear dest) with inverse-swizzled global src.
__global__ __launch_bounds__(256)
void dilated_attn_kernel(const float* __restrict__ Q,
                         const ushort_t* __restrict__ Kg,
                         const ushort_t* __restrict__ VgT,
                         const int* __restrict__ is_causal_p,
                         float* __restrict__ Out,
                         float* __restrict__ l_acc)
{
    const int HD = 768;
    // LPT-ish: heaviest q-tiles first; c = chunk index (empties exit fast)
    const int bx  = blockIdx.x;              // 0..3071
    const int qt  = 63 - (bx / 48);
    const int rem = bx % 48;
    const int h   = rem % 12;
    const int c   = rem / 12;                // 0..3
    const int group = h >> 2;
    const int sl    = 1024 << group;
    const int causal = (*is_causal_p) != 0;

    const int q0 = qt << 6;
    const int qb = q0 & (sl - 1);
    const int seg_start = q0 - qb;           // segment base (same in gathered space)
    const int diag_kt = qb >> 6;
    const int nkt = causal ? (diag_kt + 1) : (sl >> 6);
    const int kt0 = c << 4;
    if (kt0 >= nkt) return;
    const int kend = min(kt0 + 16, nkt);
    const int nch  = (nkt + 15) >> 4;

    const int tid  = threadIdx.x;
    const int wave = tid >> 6;
    const int lane = tid & 63;
    const int l15  = lane & 15;
    const int quad = lane >> 4;

    __shared__ __align__(16) __bf16 Ks[2][64 * 64];   // [key][d], swizzled
    __shared__ __align__(16) __bf16 Vs[2][64 * 64];   // [d][key], swizzled
    __shared__ __align__(16) __bf16 Ps[4][16 * 64];   // per-wave P [row][key], swizzled

    const ushort_t* kg_head = Kg + (size_t)h * 4096 * 64;
    const ushort_t* vt_head = VgT + (size_t)h * 64 * 4096;

    // staging: wave w covers rows w*16..w*16+15 (two 8-row issues per buffer).
    // lane-linear LDS slot (row = base + lane>>3, blkpos = lane&7) must receive
    // global col-block blk = blkpos ^ (row&7); row&7 == lane>>3 here.
    const int bx16  = ((lane & 7) ^ (lane >> 3)) << 3;          // inverse-swizzled col (elems)
    const int krow0 = wave * 16 + (lane >> 3);
    const int koff0 = krow0 * 64 + bx16;                         // K src offset, issue 0
    const int koff1 = koff0 + 8 * 64;                            // issue 1 (+8 rows)
    const size_t voff0 = (size_t)krow0 * 4096 + bx16;            // V src offset, issue 0
    const size_t voff1 = voff0 + (size_t)8 * 4096;               // issue 1

    auto stage = [&](int kt, int buf) {
        const ushort_t* kb = kg_head + ((size_t)(seg_start + (kt << 6)) << 6);
        const ushort_t* vb = vt_head + seg_start + (kt << 6);
        __bf16* kl = &Ks[buf][wave * 1024];
        __bf16* vl = &Vs[buf][wave * 1024];
        gld_lds16(kb + koff0, kl);
        gld_lds16(kb + koff1, kl + 512);
        gld_lds16(vb + voff0, vl);
        gld_lds16(vb + voff1, vl + 512);
    };

    // ---- Q fragments (A-layout), scale = 0.125 * log2(e) ----
    const int qrow = q0 + wave * 16 + l15;
    const float* qptr = Q + (size_t)qrow * HD + h * 64;
    bf16x8 a0, a1;
    {
        const float s = 0.125f * 1.4426950408889634f;
        float4 x0 = ((const float4*)(qptr + quad * 8))[0];
        float4 x1 = ((const float4*)(qptr + quad * 8))[1];
        float4 y0 = ((const float4*)(qptr + 32 + quad * 8))[0];
        float4 y1 = ((const float4*)(qptr + 32 + quad * 8))[1];
        a0[0]=(__bf16)(x0.x*s); a0[1]=(__bf16)(x0.y*s); a0[2]=(__bf16)(x0.z*s); a0[3]=(__bf16)(x0.w*s);
        a0[4]=(__bf16)(x1.x*s); a0[5]=(__bf16)(x1.y*s); a0[6]=(__bf16)(x1.z*s); a0[7]=(__bf16)(x1.w*s);
        a1[0]=(__bf16)(y0.x*s); a1[1]=(__bf16)(y0.y*s); a1[2]=(__bf16)(y0.z*s); a1[3]=(__bf16)(y0.w*s);
        a1[4]=(__bf16)(y1.x*s); a1[5]=(__bf16)(y1.y*s); a1[6]=(__bf16)(y1.z*s); a1[7]=(__bf16)(y1.w*s);
    }

    f32x4 o[4];
    #pragma unroll
    for (int t = 0; t < 4; ++t) o[t] = (f32x4){0.f, 0.f, 0.f, 0.f};
    float l_r[4] = {0.f, 0.f, 0.f, 0.f};

    stage(kt0, 0);
    __syncthreads();   // drains vmcnt(0): staged tile visible to all waves

    for (int kt = kt0; kt < kend; ++kt) {
        const int cur = (kt - kt0) & 1;
        if (kt + 1 < kend) stage(kt + 1, cur ^ 1);   // async; lands by next barrier

        // ---- S = (Q*scale*log2e) K^T ----
        f32x4 sacc[4];
        __builtin_amdgcn_s_setprio(1);
        #pragma unroll
        for (int t = 0; t < 4; ++t) {
            const int krow = t * 16 + l15;
            const int xk = (krow & 7) << 3;
            bf16x8 b0 = *(const bf16x8*)&Ks[cur][krow * 64 + ((quad << 3) ^ xk)];
            bf16x8 b1 = *(const bf16x8*)&Ks[cur][krow * 64 + (((quad + 4) << 3) ^ xk)];
            f32x4 cc = (f32x4){0.f, 0.f, 0.f, 0.f};
            cc = __builtin_amdgcn_mfma_f32_16x16x32_bf16(a0, b0, cc, 0, 0, 0);
            cc = __builtin_amdgcn_mfma_f32_16x16x32_bf16(a1, b1, cc, 0, 0, 0);
            sacc[t] = cc;
        }
        __builtin_amdgcn_s_setprio(0);

        // ---- P = 2^S (no max subtraction; no cross-lane ops in loop) ----
        const bool isdiag = causal && (kt == diag_kt);
        #pragma unroll
        for (int t = 0; t < 4; ++t) {
            const int col = t * 16 + l15;
            const int cb  = t * 2 + (l15 >> 3);      // col>>3
            #pragma unroll
            for (int r = 0; r < 4; ++r) {
                const int prow = quad * 4 + r;
                const int row = wave * 16 + prow;
                float p = exp2f(sacc[t][r]);
                if (isdiag && col > row) p = 0.f;
                l_r[r] += p;
                Ps[wave][prow * 64 + ((cb ^ (prow & 7)) << 3) + (l15 & 7)] = (__bf16)p;
            }
        }

        // ---- O += P V ----
        const int xp = (l15 & 7) << 3;
        bf16x8 p0 = *(const bf16x8*)&Ps[wave][l15 * 64 + ((quad << 3) ^ xp)];
        bf16x8 p1 = *(const bf16x8*)&Ps[wave][l15 * 64 + (((quad + 4) << 3) ^ xp)];
        __builtin_amdgcn_s_setprio(1);
        #pragma unroll
        for (int t = 0; t < 4; ++t) {
            const int vrow = t * 16 + l15;
            const int xv = (vrow & 7) << 3;
            bf16x8 bv0 = *(const bf16x8*)&Vs[cur][vrow * 64 + ((quad << 3) ^ xv)];
            bf16x8 bv1 = *(const bf16x8*)&Vs[cur][vrow * 64 + (((quad + 4) << 3) ^ xv)];
            o[t] = __builtin_amdgcn_mfma_f32_16x16x32_bf16(p0, bv0, o[t], 0, 0, 0);
            o[t] = __builtin_amdgcn_mfma_f32_16x16x32_bf16(p1, bv1, o[t], 0, 0, 0);
        }
        __builtin_amdgcn_s_setprio(0);

        __syncthreads();   // buffer handoff + drains prefetch vmcnt
    }

    // ---- epilogue ----
    #pragma unroll
    for (int off = 1; off < 16; off <<= 1) {
        #pragma unroll
        for (int r = 0; r < 4; ++r)
            l_r[r] += __shfl_xor(l_r[r], off, 64);
    }
    if (nch == 1) {
        #pragma unroll
        for (int r = 0; r < 4; ++r) {
            const float inv = 1.0f / l_r[r];
            const int row = q0 + wave * 16 + quad * 4 + r;
            #pragma unroll
            for (int t = 0; t < 4; ++t)
                Out[(size_t)row * HD + h * 64 + t * 16 + l15] = o[t][r] * inv;
        }
    } else {
        #pragma unroll
        for (int r = 0; r < 4; ++r) {
            const int row = q0 + wave * 16 + quad * 4 + r;
            if (l15 == 0) atomicAdd(&l_acc[row * 12 + h], l_r[r]);
            #pragma unroll
            for (int t = 0; t < 4; ++t)
                atomicAdd(&Out[(size_t)row * HD + h * 64 + t * 16 + l15], o[t][r]);
        }
    }
}

// ---------------- finalize: divide multi-chunk rows by accumulated l ----------------
__global__ __launch_bounds__(256)
void finalize_kernel(float* __restrict__ Out, const float* __restrict__ l_acc,
                     const int* __restrict__ is_causal_p)
{
    const int causal = (*is_causal_p) != 0;
    const int idx = blockIdx.x * 256 + threadIdx.x;   // 0..786431 (float4 units)
    const int rh = idx >> 4;
    const int d4 = idx & 15;
    const int h = rh % 12;
    const int row = rh / 12;
    const int group = h >> 2;
    const int ntf = 16 << group;
    const int qt = row >> 6;
    const int nkt = causal ? ((qt & (ntf - 1)) + 1) : ntf;
    if (nkt <= 16) return;                            // single chunk: already normalized
    const float inv = 1.0f / l_acc[rh];
    float4* p = (float4*)Out + (size_t)rh * 16 + d4;
    float4 v = *p;
    v.x *= inv; v.y *= inv; v.z *= inv; v.w *= inv;
    *p = v;
}

extern "C" void kernel_launch(void* const* d_in, const int* in_sizes, int n_in,
                              void* d_out, int out_size, void* d_ws, size_t ws_size,
                              hipStream_t stream) {
    (void)in_sizes; (void)n_in; (void)out_size; (void)ws_size;
    const float* Q = (const float*)d_in[0];
    const float* K = (const float*)d_in[1];
    const float* V = (const float*)d_in[2];
    const int* isc = (const int*)d_in[3];
    float* Out = (float*)d_out;
    ushort_t* Kg   = (ushort_t*)((char*)d_ws + KG_OFF);
    ushort_t* VgT  = (ushort_t*)((char*)d_ws + VGT_OFF);
    float*    lacc = (float*)((char*)d_ws + LACC_OFF);

    hipMemsetAsync(Out, 0, (size_t)4096 * 12 * 64 * 4, stream);
    hipMemsetAsync(lacc, 0, (size_t)4096 * 12 * 4, stream);
    preconvert_kernel<<<1536, 256, 0, stream>>>(K, V, Kg, VgT);
    dilated_attn_kernel<<<3072, 256, 0, stream>>>(Q, Kg, VgT, isc, Out, lacc);
    finalize_kernel<<<3072, 256, 0, stream>>>(Out, lacc, isc);
}

// Round 2
// 148.657 us; speedup vs baseline: 1.0445x; 1.0445x over previous
//
#include <hip/hip_runtime.h>
#include <hip/hip_bf16.h>
#include <math.h>

typedef __bf16 bf16x8 __attribute__((ext_vector_type(8)));
typedef float  f32x4  __attribute__((ext_vector_type(4)));
typedef float  f32x16 __attribute__((ext_vector_type(16)));
typedef unsigned int uint4v __attribute__((ext_vector_type(4)));
typedef unsigned short ushort_t;

#define LDK 72   // padded LDS row for preconvert transpose only

// ws layout (bytes):
//   Kg  : [12][4096][64] bf16  (gathered, per-head)          @ 0        (6291456)
//   VgT : [12][64][4096] bf16  (gathered, transposed)        @ 6291456  (6291456)
//   l_acc: [4096*12] f32                                     @ 12582912 (196608)
#define KG_OFF  0
#define VGT_OFF 6291456
#define LACC_OFF 12582912

__device__ __forceinline__ int gather_pos(int gi, int group) {
    const int lsl = 10 + group;           // log2(segment length)
    const int seg = gi >> lsl;
    const int j   = gi - (seg << lsl);
    return (seg << lsl) + group + ((j & 1023) << group);
}

// async 16B global->LDS (lane-linear LDS dest: base + lane*16)
__device__ __forceinline__ void gld_lds16(const ushort_t* g, __bf16* l) {
    __builtin_amdgcn_global_load_lds(
        (const __attribute__((address_space(1))) void*)g,
        (__attribute__((address_space(3))) void*)l, 16, 0, 0);
}

__device__ __forceinline__ unsigned int pk_bf16(float lo, float hi) {
    unsigned short a = __builtin_bit_cast(unsigned short, (__bf16)lo);
    unsigned short b = __builtin_bit_cast(unsigned short, (__bf16)hi);
    return ((unsigned int)b << 16) | (unsigned int)a;
}

__device__ __forceinline__ f32x16 zero16() {
    f32x16 z;
    #pragma unroll
    for (int i = 0; i < 16; ++i) z[i] = 0.f;
    return z;
}

// ---------------- pre-convert kernel: fp32 -> bf16, gather + transpose ----------------
__global__ __launch_bounds__(256)
void preconvert_kernel(const float* __restrict__ K, const float* __restrict__ V,
                       ushort_t* __restrict__ Kg, ushort_t* __restrict__ VgT)
{
    const int HD = 768;
    int b = blockIdx.x;
    const int tid = threadIdx.x;
    if (b < 768) {
        // K part: Kg[h][gi][d]
        const int h = b % 12, gi0 = (b / 12) * 64;
        const int group = h >> 2;
        const int gi = gi0 + (tid >> 2);
        const int d0 = (tid & 3) << 4;
        const int pos = gather_pos(gi, group);
        const float* kp = K + (size_t)pos * HD + h * 64 + d0;
        float4 x0 = ((const float4*)kp)[0], x1 = ((const float4*)kp)[1];
        float4 x2 = ((const float4*)kp)[2], x3 = ((const float4*)kp)[3];
        bf16x8 w0, w1;
        w0[0]=(__bf16)x0.x; w0[1]=(__bf16)x0.y; w0[2]=(__bf16)x0.z; w0[3]=(__bf16)x0.w;
        w0[4]=(__bf16)x1.x; w0[5]=(__bf16)x1.y; w0[6]=(__bf16)x1.z; w0[7]=(__bf16)x1.w;
        w1[0]=(__bf16)x2.x; w1[1]=(__bf16)x2.y; w1[2]=(__bf16)x2.z; w1[3]=(__bf16)x2.w;
        w1[4]=(__bf16)x3.x; w1[5]=(__bf16)x3.y; w1[6]=(__bf16)x3.z; w1[7]=(__bf16)x3.w;
        ushort_t* out = Kg + ((size_t)(h * 4096 + gi)) * 64 + d0;
        *(bf16x8*)out = w0;
        *(bf16x8*)(out + 8) = w1;
    } else {
        // V part: VgT[h][d][gi] via LDS transpose
        b -= 768;
        const int h = b % 12, gi0 = (b / 12) * 64;
        const int group = h >> 2;
        __shared__ __align__(16) __bf16 Ts[64 * LDK];
        const int gil = tid >> 2;
        const int d0 = (tid & 3) << 4;
        const int pos = gather_pos(gi0 + gil, group);
        const float* vp = V + (size_t)pos * HD + h * 64 + d0;
        float4 x0 = ((const float4*)vp)[0], x1 = ((const float4*)vp)[1];
        float4 x2 = ((const float4*)vp)[2], x3 = ((const float4*)vp)[3];
        bf16x8 w0, w1;
        w0[0]=(__bf16)x0.x; w0[1]=(__bf16)x0.y; w0[2]=(__bf16)x0.z; w0[3]=(__bf16)x0.w;
        w0[4]=(__bf16)x1.x; w0[5]=(__bf16)x1.y; w0[6]=(__bf16)x1.z; w0[7]=(__bf16)x1.w;
        w1[0]=(__bf16)x2.x; w1[1]=(__bf16)x2.y; w1[2]=(__bf16)x2.z; w1[3]=(__bf16)x2.w;
        w1[4]=(__bf16)x3.x; w1[5]=(__bf16)x3.y; w1[6]=(__bf16)x3.z; w1[7]=(__bf16)x3.w;
        *(bf16x8*)&Ts[gil * LDK + d0]     = w0;
        *(bf16x8*)&Ts[gil * LDK + d0 + 8] = w1;
        __syncthreads();
        const int d = tid >> 2, c = tid & 3;
        bf16x8 o0, o1;
        #pragma unroll
        for (int i = 0; i < 8; ++i) {
            o0[i] = Ts[(c * 16 + i) * LDK + d];
            o1[i] = Ts[(c * 16 + 8 + i) * LDK + d];
        }
        ushort_t* out = VgT + ((size_t)(h * 64 + d)) * 4096 + gi0 + c * 16;
        *(bf16x8*)out = o0;
        *(bf16x8*)(out + 8) = o1;
    }
}

// ---------------- main attention kernel ----------------
// 128 q-rows/block, 4 waves x 32 q-rows, 32x32x16 MFMA, swapped QK^T,
// fully in-register softmax (no P LDS round-trip).
// LDS tiles: unpadded 128B rows + XOR-16B-block swizzle (both-sides, via
// inverse-swizzled global src for global_load_lds).
__global__ __launch_bounds__(256)
void dilated_attn_kernel(const float* __restrict__ Q,
                         const ushort_t* __restrict__ Kg,
                         const ushort_t* __restrict__ VgT,
                         const int* __restrict__ is_causal_p,
                         float* __restrict__ Out,
                         float* __restrict__ l_acc)
{
    const int HD = 768;
    const int bx  = blockIdx.x;              // 0..1535
    const int qt  = 31 - (bx / 48);          // 128-row q-tile, heaviest first
    const int rem = bx % 48;
    const int h   = rem % 12;
    const int c   = rem / 12;                // 0..3
    const int group = h >> 2;
    const int sl    = 1024 << group;
    const int causal = (*is_causal_p) != 0;

    const int q0 = qt << 7;
    const int qb = q0 & (sl - 1);            // 128-aligned segment offset
    const int seg_start = q0 - qb;
    const int blk_diag = (qb + 127) >> 6;    // last k-tile any row of this block needs
    const int nkt = causal ? (blk_diag + 1) : (sl >> 6);
    const int kt0 = c << 4;
    if (kt0 >= nkt) return;
    const int kend = min(kt0 + 16, nkt);
    const int nch  = (nkt + 15) >> 4;

    const int tid  = threadIdx.x;
    const int wave = tid >> 6;
    const int lane = tid & 63;
    const int l31  = lane & 31;
    const int hi   = lane >> 5;

    __shared__ __align__(16) __bf16 Ks[2][64 * 64];   // [key][d], swizzled
    __shared__ __align__(16) __bf16 Vs[2][64 * 64];   // [d][key], swizzled

    const ushort_t* kg_head = Kg + (size_t)h * 4096 * 64;
    const ushort_t* vt_head = VgT + (size_t)h * 64 * 4096;

    // ---- staging: per wave, per issue i: 8 rows (64 lanes x 16B = 1KB) ----
    // row = i*32 + wave*8 + (lane>>3); lane-linear LDS slot (blkpos = lane&7)
    // receives global col-block blk = blkpos ^ (row&7); row&7 == (lane>>3)&7.
    const int bx16 = (((lane & 7) ^ (lane >> 3)) & 7) << 3;   // inverse-swizzled col (elems)
    const int r8   = lane >> 3;                               // 0..7

    auto stage = [&](int kt, int buf) {
        const ushort_t* kb = kg_head + ((size_t)(seg_start + (kt << 6)) << 6);
        const ushort_t* vb = vt_head + seg_start + (kt << 6);
        #pragma unroll
        for (int i = 0; i < 2; ++i) {
            const int row = i * 32 + wave * 8 + r8;
            gld_lds16(kb + row * 64 + bx16, &Ks[buf][(i * 32 + wave * 8) * 64]);
            gld_lds16(vb + (size_t)row * 4096 + bx16, &Vs[buf][(i * 32 + wave * 8) * 64]);
        }
    };

    // ---- Q fragments: lane (hi,l31) holds Q[q0+wave*32+l31][ds*16+hi*8 .. +8] ----
    const int qrow = q0 + wave * 32 + l31;
    const float* qptr = Q + (size_t)qrow * HD + h * 64;
    bf16x8 qf[4];
    {
        const float s = 0.125f * 1.4426950408889634f;
        #pragma unroll
        for (int ds = 0; ds < 4; ++ds) {
            float4 x0 = ((const float4*)(qptr + ds * 16 + hi * 8))[0];
            float4 x1 = ((const float4*)(qptr + ds * 16 + hi * 8))[1];
            bf16x8 w;
            w[0]=(__bf16)(x0.x*s); w[1]=(__bf16)(x0.y*s); w[2]=(__bf16)(x0.z*s); w[3]=(__bf16)(x0.w*s);
            w[4]=(__bf16)(x1.x*s); w[5]=(__bf16)(x1.y*s); w[6]=(__bf16)(x1.z*s); w[7]=(__bf16)(x1.w*s);
            qf[ds] = w;
        }
    }

    // per-wave diag tile; waves 0,1 -> qb/64; waves 2,3 -> qb/64+1
    const int mydiag = causal ? ((qb + wave * 32 + 31) >> 6) : 0x7fffffff;
    const int lrow   = ((wave & 1) << 5) + l31;   // local row within the diag tile

    f32x16 o0 = zero16(), o1 = zero16();          // O[q][d0..31], O[q][d32..63]
    float l_part = 0.f;

    stage(kt0, 0);
    __syncthreads();

    for (int kt = kt0; kt < kend; ++kt) {
        const int cur = (kt - kt0) & 1;
        if (kt + 1 < kend) stage(kt + 1, cur ^ 1);   // async; lands by next barrier

        if (kt <= mydiag) {
            // ---- S^T = K Q^T : col = q (lane-local), row = key ----
            f32x16 s0 = zero16(), s1 = zero16();
            const int xr = (l31 & 7);
            __builtin_amdgcn_s_setprio(1);
            #pragma unroll
            for (int ds = 0; ds < 4; ++ds) {
                const int cb = ds * 2 + hi;
                bf16x8 k0 = *(const bf16x8*)&Ks[cur][l31 * 64        + ((cb ^ xr) << 3)];
                bf16x8 k1 = *(const bf16x8*)&Ks[cur][(32 + l31) * 64 + ((cb ^ xr) << 3)];
                s0 = __builtin_amdgcn_mfma_f32_32x32x16_bf16(k0, qf[ds], s0, 0, 0, 0);
                s1 = __builtin_amdgcn_mfma_f32_32x32x16_bf16(k1, qf[ds], s1, 0, 0, 0);
            }
            __builtin_amdgcn_s_setprio(0);

            // ---- P = 2^S, in-register, causal mask on the diag tile ----
            float p[2][16];
            const bool isdiag = causal && (kt == mydiag);
            #pragma unroll
            for (int r = 0; r < 16; ++r) {
                float v0 = exp2f(s0[r]);
                float v1 = exp2f(s1[r]);
                if (isdiag) {
                    const int kl = (r & 3) + ((r >> 2) << 3) + (hi << 2);
                    if (kl > lrow)      v0 = 0.f;
                    if (kl + 32 > lrow) v1 = 0.f;
                }
                p[0][r] = v0; p[1][r] = v1;
                l_part += v0 + v1;
            }

            // ---- pack bf16 + half-swap -> PV A-frags; O += P V ----
            __builtin_amdgcn_s_setprio(1);
            #pragma unroll
            for (int b = 0; b < 2; ++b) {           // key block: 0 -> keys 0-31, 1 -> 32-63
                #pragma unroll
                for (int ks2 = 0; ks2 < 2; ++ks2) { // k-slice within block (16 keys)
                    const int g = ks2 * 8;
                    unsigned int x0 = pk_bf16(p[b][g + 0], p[b][g + 1]);
                    unsigned int x1 = pk_bf16(p[b][g + 2], p[b][g + 3]);
                    unsigned int y0 = pk_bf16(p[b][g + 4], p[b][g + 5]);
                    unsigned int y1 = pk_bf16(p[b][g + 6], p[b][g + 7]);
                    unsigned int sx0 = (unsigned int)__shfl_xor((int)x0, 32);
                    unsigned int sx1 = (unsigned int)__shfl_xor((int)x1, 32);
                    unsigned int sy0 = (unsigned int)__shfl_xor((int)y0, 32);
                    unsigned int sy1 = (unsigned int)__shfl_xor((int)y1, 32);
                    uint4v t;
                    t[0] = hi ? sy0 : x0;
                    t[1] = hi ? sy1 : x1;
                    t[2] = hi ? y0 : sx0;
                    t[3] = hi ? y1 : sx1;
                    bf16x8 pa = __builtin_bit_cast(bf16x8, t);
                    // V B-frags: keys (b*2+ks2)*16 + hi*8, cols d = {l31, 32+l31}
                    const int kcb = (b * 2 + ks2) * 2 + hi;
                    bf16x8 v0 = *(const bf16x8*)&Vs[cur][l31 * 64        + ((kcb ^ xr) << 3)];
                    bf16x8 v1 = *(const bf16x8*)&Vs[cur][(32 + l31) * 64 + ((kcb ^ xr) << 3)];
                    o0 = __builtin_amdgcn_mfma_f32_32x32x16_bf16(pa, v0, o0, 0, 0, 0);
                    o1 = __builtin_amdgcn_mfma_f32_32x32x16_bf16(pa, v1, o1, 0, 0, 0);
                }
            }
            __builtin_amdgcn_s_setprio(0);
        }

        __syncthreads();   // buffer handoff + drains prefetch vmcnt
    }

    // ---- epilogue: l lives per q-column (lane l31); O rows need redistribution ----
    const float l2 = l_part + __shfl_xor(l_part, 32);   // full denom for q = qw + l31
    const int qw = q0 + wave * 32;
    if (nch == 1) {
        const float inv = 1.0f / l2;
        #pragma unroll
        for (int r = 0; r < 16; ++r) {
            const int qloc = (r & 3) + ((r >> 2) << 3) + (hi << 2);
            const float invq = __shfl(inv, qloc);       // lane qloc holds inv for q=qw+qloc
            const int row = qw + qloc;
            Out[(size_t)row * HD + h * 64 + l31]      = o0[r] * invq;
            Out[(size_t)row * HD + h * 64 + 32 + l31] = o1[r] * invq;
        }
    } else {
        if (hi == 0) atomicAdd(&l_acc[(qw + l31) * 12 + h], l2);
        #pragma unroll
        for (int r = 0; r < 16; ++r) {
            const int qloc = (r & 3) + ((r >> 2) << 3) + (hi << 2);
            const int row = qw + qloc;
            atomicAdd(&Out[(size_t)row * HD + h * 64 + l31],      o0[r]);
            atomicAdd(&Out[(size_t)row * HD + h * 64 + 32 + l31], o1[r]);
        }
    }
}

// ---------------- finalize: divide multi-chunk rows by accumulated l ----------------
__global__ __launch_bounds__(256)
void finalize_kernel(float* __restrict__ Out, const float* __restrict__ l_acc,
                     const int* __restrict__ is_causal_p)
{
    const int causal = (*is_causal_p) != 0;
    const int idx = blockIdx.x * 256 + threadIdx.x;   // 0..786431 (float4 units)
    const int rh = idx >> 4;
    const int d4 = idx & 15;
    const int h = rh % 12;
    const int row = rh / 12;
    const int group = h >> 2;
    const int ntf = 16 << group;                      // k-tiles per segment
    const int qt128 = row >> 7;
    const int qb_t = (qt128 << 1) & (ntf - 1);        // block qb in 64-tiles
    const int nkt = causal ? (qb_t + 2) : ntf;
    if (nkt <= 16) return;                            // single chunk: already normalized
    const float inv = 1.0f / l_acc[rh];
    float4* p = (float4*)Out + (size_t)rh * 16 + d4;
    float4 v = *p;
    v.x *= inv; v.y *= inv; v.z *= inv; v.w *= inv;
    *p = v;
}

extern "C" void kernel_launch(void* const* d_in, const int* in_sizes, int n_in,
                              void* d_out, int out_size, void* d_ws, size_t ws_size,
                              hipStream_t stream) {
    (void)in_sizes; (void)n_in; (void)out_size; (void)ws_size;
    const float* Q = (const float*)d_in[0];
    const float* K = (const float*)d_in[1];
    const float* V = (const float*)d_in[2];
    const int* isc = (const int*)d_in[3];
    float* Out = (float*)d_out;
    ushort_t* Kg   = (ushort_t*)((char*)d_ws + KG_OFF);
    ushort_t* VgT  = (ushort_t*)((char*)d_ws + VGT_OFF);
    float*    lacc = (float*)((char*)d_ws + LACC_OFF);

    hipMemsetAsync(Out, 0, (size_t)4096 * 12 * 64 * 4, stream);
    hipMemsetAsync(lacc, 0, (size_t)4096 * 12 * 4, stream);
    preconvert_kernel<<<1536, 256, 0, stream>>>(K, V, Kg, VgT);
    dilated_attn_kernel<<<1536, 256, 0, stream>>>(Q, Kg, VgT, isc, Out, lacc);
    finalize_kernel<<<3072, 256, 0, stream>>>(Out, lacc, isc);
}

// Round 3
// 143.038 us; speedup vs baseline: 1.0855x; 1.0393x over previous
//
#include <hip/hip_runtime.h>
#include <hip/hip_bf16.h>
#include <math.h>

typedef __bf16 bf16x8 __attribute__((ext_vector_type(8)));
typedef float  f32x4  __attribute__((ext_vector_type(4)));
typedef float  f32x16 __attribute__((ext_vector_type(16)));
typedef int    int2v  __attribute__((ext_vector_type(2)));
typedef unsigned int uint4v __attribute__((ext_vector_type(4)));
typedef unsigned short ushort_t;

#define LDK 72   // padded LDS row for preconvert transpose only

// ws layout (bytes):
//   Kg  : [12][4096][64] bf16  (gathered, per-head)          @ 0        (6291456)
//   VgT : [12][64][4096] bf16  (gathered, transposed)        @ 6291456  (6291456)
//   l_acc: [4096*12] f32                                     @ 12582912 (196608)
#define KG_OFF  0
#define VGT_OFF 6291456
#define LACC_OFF 12582912

__device__ __forceinline__ int gather_pos(int gi, int group) {
    const int lsl = 10 + group;           // log2(segment length)
    const int seg = gi >> lsl;
    const int j   = gi - (seg << lsl);
    return (seg << lsl) + group + ((j & 1023) << group);
}

// async 16B global->LDS (lane-linear LDS dest: base + lane*16)
__device__ __forceinline__ void gld_lds16(const ushort_t* g, __bf16* l) {
    __builtin_amdgcn_global_load_lds(
        (const __attribute__((address_space(1))) void*)g,
        (__attribute__((address_space(3))) void*)l, 16, 0, 0);
}

__device__ __forceinline__ unsigned int pk_bf16(float lo, float hi) {
    unsigned short a = __builtin_bit_cast(unsigned short, (__bf16)lo);
    unsigned short b = __builtin_bit_cast(unsigned short, (__bf16)hi);
    return ((unsigned int)b << 16) | (unsigned int)a;
}

__device__ __forceinline__ f32x16 zero16() {
    f32x16 z;
    #pragma unroll
    for (int i = 0; i < 16; ++i) z[i] = 0.f;
    return z;
}

// ---------------- pre-convert kernel: fp32 -> bf16, gather + transpose ----------------
// Also zeroes Out and l_acc (replaces the two hipMemsetAsync launches).
__global__ __launch_bounds__(256)
void preconvert_kernel(const float* __restrict__ K, const float* __restrict__ V,
                       ushort_t* __restrict__ Kg, ushort_t* __restrict__ VgT,
                       float* __restrict__ Out, float* __restrict__ l_acc)
{
    const int HD = 768;
    int b = blockIdx.x;
    const int tid = threadIdx.x;
    if (b < 768) {
        // zero Out: 196608 threads x 4 float4 = 12.58 MB
        {
            float4 z = {0.f, 0.f, 0.f, 0.f};
            float4* zp = (float4*)Out + ((size_t)b * 256 + tid) * 4;
            zp[0] = z; zp[1] = z; zp[2] = z; zp[3] = z;
        }
        // K part: Kg[h][gi][d]
        const int h = b % 12, gi0 = (b / 12) * 64;
        const int group = h >> 2;
        const int gi = gi0 + (tid >> 2);
        const int d0 = (tid & 3) << 4;
        const int pos = gather_pos(gi, group);
        const float* kp = K + (size_t)pos * HD + h * 64 + d0;
        float4 x0 = ((const float4*)kp)[0], x1 = ((const float4*)kp)[1];
        float4 x2 = ((const float4*)kp)[2], x3 = ((const float4*)kp)[3];
        bf16x8 w0, w1;
        w0[0]=(__bf16)x0.x; w0[1]=(__bf16)x0.y; w0[2]=(__bf16)x0.z; w0[3]=(__bf16)x0.w;
        w0[4]=(__bf16)x1.x; w0[5]=(__bf16)x1.y; w0[6]=(__bf16)x1.z; w0[7]=(__bf16)x1.w;
        w1[0]=(__bf16)x2.x; w1[1]=(__bf16)x2.y; w1[2]=(__bf16)x2.z; w1[3]=(__bf16)x2.w;
        w1[4]=(__bf16)x3.x; w1[5]=(__bf16)x3.y; w1[6]=(__bf16)x3.z; w1[7]=(__bf16)x3.w;
        ushort_t* out = Kg + ((size_t)(h * 4096 + gi)) * 64 + d0;
        *(bf16x8*)out = w0;
        *(bf16x8*)(out + 8) = w1;
    } else {
        // V part: VgT[h][d][gi] via LDS transpose
        b -= 768;
        if (b < 192) l_acc[b * 256 + tid] = 0.f;   // zero l_acc: 49152 floats
        const int h = b % 12, gi0 = (b / 12) * 64;
        const int group = h >> 2;
        __shared__ __align__(16) __bf16 Ts[64 * LDK];
        const int gil = tid >> 2;
        const int d0 = (tid & 3) << 4;
        const int pos = gather_pos(gi0 + gil, group);
        const float* vp = V + (size_t)pos * HD + h * 64 + d0;
        float4 x0 = ((const float4*)vp)[0], x1 = ((const float4*)vp)[1];
        float4 x2 = ((const float4*)vp)[2], x3 = ((const float4*)vp)[3];
        bf16x8 w0, w1;
        w0[0]=(__bf16)x0.x; w0[1]=(__bf16)x0.y; w0[2]=(__bf16)x0.z; w0[3]=(__bf16)x0.w;
        w0[4]=(__bf16)x1.x; w0[5]=(__bf16)x1.y; w0[6]=(__bf16)x1.z; w0[7]=(__bf16)x1.w;
        w1[0]=(__bf16)x2.x; w1[1]=(__bf16)x2.y; w1[2]=(__bf16)x2.z; w1[3]=(__bf16)x2.w;
        w1[4]=(__bf16)x3.x; w1[5]=(__bf16)x3.y; w1[6]=(__bf16)x3.z; w1[7]=(__bf16)x3.w;
        *(bf16x8*)&Ts[gil * LDK + d0]     = w0;
        *(bf16x8*)&Ts[gil * LDK + d0 + 8] = w1;
        __syncthreads();
        const int d = tid >> 2, c = tid & 3;
        bf16x8 o0, o1;
        #pragma unroll
        for (int i = 0; i < 8; ++i) {
            o0[i] = Ts[(c * 16 + i) * LDK + d];
            o1[i] = Ts[(c * 16 + 8 + i) * LDK + d];
        }
        ushort_t* out = VgT + ((size_t)(h * 64 + d)) * 4096 + gi0 + c * 16;
        *(bf16x8*)out = o0;
        *(bf16x8*)(out + 8) = o1;
    }
}

// ---------------- main attention kernel ----------------
// 128 q-rows/block, 4 waves x 32 q-rows, 32x32x16 MFMA, swapped QK^T,
// fully in-register softmax, permlane32_swap P-redistribution.
// Counted-wait raw-barrier pipeline: ONE s_barrier per k-tile, no vmcnt drain
// at the barrier (stage(kt) waited a full tile after issue).
__global__ __launch_bounds__(256)
void dilated_attn_kernel(const float* __restrict__ Q,
                         const ushort_t* __restrict__ Kg,
                         const ushort_t* __restrict__ VgT,
                         const int* __restrict__ is_causal_p,
                         float* __restrict__ Out,
                         float* __restrict__ l_acc)
{
    const int HD = 768;
    const int bx  = blockIdx.x;              // 0..1535
    const int qt  = 31 - (bx / 48);          // 128-row q-tile, heaviest first
    const int rem = bx % 48;
    const int h   = rem % 12;
    const int c   = rem / 12;                // 0..3
    const int group = h >> 2;
    const int sl    = 1024 << group;
    const int causal = (*is_causal_p) != 0;

    const int q0 = qt << 7;
    const int qb = q0 & (sl - 1);            // 128-aligned segment offset
    const int seg_start = q0 - qb;
    const int blk_diag = (qb + 127) >> 6;    // last k-tile any row of this block needs
    const int nkt = causal ? (blk_diag + 1) : (sl >> 6);
    const int kt0 = c << 4;
    if (kt0 >= nkt) return;
    const int kend = min(kt0 + 16, nkt);
    const int nch  = (nkt + 15) >> 4;

    const int tid  = threadIdx.x;
    const int wave = tid >> 6;
    const int lane = tid & 63;
    const int l31  = lane & 31;
    const int hi   = lane >> 5;

    __shared__ __align__(16) __bf16 Ks[2][64 * 64];   // [key][d], swizzled
    __shared__ __align__(16) __bf16 Vs[2][64 * 64];   // [d][key], swizzled

    const ushort_t* kg_head = Kg + (size_t)h * 4096 * 64;
    const ushort_t* vt_head = VgT + (size_t)h * 64 * 4096;

    // staging: per wave, per issue i: 8 rows (64 lanes x 16B = 1KB)
    const int bx16 = (((lane & 7) ^ (lane >> 3)) & 7) << 3;   // inverse-swizzled col (elems)
    const int r8   = lane >> 3;                               // 0..7

    auto stage = [&](int kt, int buf) {
        const ushort_t* kb = kg_head + ((size_t)(seg_start + (kt << 6)) << 6);
        const ushort_t* vb = vt_head + seg_start + (kt << 6);
        #pragma unroll
        for (int i = 0; i < 2; ++i) {
            const int row = i * 32 + wave * 8 + r8;
            gld_lds16(kb + row * 64 + bx16, &Ks[buf][(i * 32 + wave * 8) * 64]);
            gld_lds16(vb + (size_t)row * 4096 + bx16, &Vs[buf][(i * 32 + wave * 8) * 64]);
        }
    };

    stage(kt0, 0);   // issue first tile before the (long-latency) Q loads

    // ---- Q fragments: lane (hi,l31) holds Q[q0+wave*32+l31][ds*16+hi*8 .. +8] ----
    const int qrow = q0 + wave * 32 + l31;
    const float* qptr = Q + (size_t)qrow * HD + h * 64;
    bf16x8 qf[4];
    {
        const float s = 0.125f * 1.4426950408889634f;
        #pragma unroll
        for (int ds = 0; ds < 4; ++ds) {
            float4 x0 = ((const float4*)(qptr + ds * 16 + hi * 8))[0];
            float4 x1 = ((const float4*)(qptr + ds * 16 + hi * 8))[1];
            bf16x8 w;
            w[0]=(__bf16)(x0.x*s); w[1]=(__bf16)(x0.y*s); w[2]=(__bf16)(x0.z*s); w[3]=(__bf16)(x0.w*s);
            w[4]=(__bf16)(x1.x*s); w[5]=(__bf16)(x1.y*s); w[6]=(__bf16)(x1.z*s); w[7]=(__bf16)(x1.w*s);
            qf[ds] = w;
        }
    }

    // per-wave diag tile; waves 0,1 -> qb/64; waves 2,3 -> qb/64+1
    const int mydiag = causal ? ((qb + wave * 32 + 31) >> 6) : 0x7fffffff;
    const int lrow   = ((wave & 1) << 5) + l31;   // local row within the diag tile

    f32x16 o0 = zero16(), o1 = zero16();          // O[q][d0..31], O[q][d32..63]
    float l_part = 0.f;

    for (int kt = kt0; kt < kend; ++kt) {
        const int cur = (kt - kt0) & 1;

        // stage(kt) was issued one full tile ago -> latency hidden; no drain stall.
        asm volatile("s_waitcnt vmcnt(0)" ::: "memory");
        __builtin_amdgcn_s_barrier();             // all waves' stage(kt) landed;
        __builtin_amdgcn_sched_barrier(0);        // no motion across the barrier

        // WAR-safe here: everyone passed barrier => done reading buf cur^1 (iter kt-1)
        if (kt + 1 < kend) stage(kt + 1, cur ^ 1);

        if (kt <= mydiag) {
            // ---- S^T = K Q^T : col = q (lane-local), row = key ----
            f32x16 s0 = zero16(), s1 = zero16();
            const int xr = (l31 & 7);
            __builtin_amdgcn_s_setprio(1);
            #pragma unroll
            for (int ds = 0; ds < 4; ++ds) {
                const int cb = ds * 2 + hi;
                bf16x8 k0 = *(const bf16x8*)&Ks[cur][l31 * 64        + ((cb ^ xr) << 3)];
                bf16x8 k1 = *(const bf16x8*)&Ks[cur][(32 + l31) * 64 + ((cb ^ xr) << 3)];
                s0 = __builtin_amdgcn_mfma_f32_32x32x16_bf16(k0, qf[ds], s0, 0, 0, 0);
                s1 = __builtin_amdgcn_mfma_f32_32x32x16_bf16(k1, qf[ds], s1, 0, 0, 0);
            }
            __builtin_amdgcn_s_setprio(0);

            // ---- P = 2^S, in-register, causal mask on the diag tile ----
            float p[2][16];
            const bool isdiag = causal && (kt == mydiag);
            #pragma unroll
            for (int r = 0; r < 16; ++r) {
                float v0 = exp2f(s0[r]);
                float v1 = exp2f(s1[r]);
                if (isdiag) {
                    const int kl = (r & 3) + ((r >> 2) << 3) + (hi << 2);
                    if (kl > lrow)      v0 = 0.f;
                    if (kl + 32 > lrow) v1 = 0.f;
                }
                p[0][r] = v0; p[1][r] = v1;
                l_part += v0 + v1;
            }

            // ---- pack bf16 + permlane32_swap -> PV A-frags; O += P V ----
            __builtin_amdgcn_s_setprio(1);
            #pragma unroll
            for (int b = 0; b < 2; ++b) {           // key block: 0 -> keys 0-31, 1 -> 32-63
                #pragma unroll
                for (int ks2 = 0; ks2 < 2; ++ks2) { // k-slice within block (16 keys)
                    const int g = ks2 * 8;
                    int x0 = (int)pk_bf16(p[b][g + 0], p[b][g + 1]);
                    int x1 = (int)pk_bf16(p[b][g + 2], p[b][g + 3]);
                    int y0 = (int)pk_bf16(p[b][g + 4], p[b][g + 5]);
                    int y1 = (int)pk_bf16(p[b][g + 6], p[b][g + 7]);
                    // vdst.hi <-> vsrc.lo: (t0,t2) from (x0,y0); (t1,t3) from (x1,y1)
                    int2v r02 = __builtin_amdgcn_permlane32_swap(x0, y0, false, false);
                    int2v r13 = __builtin_amdgcn_permlane32_swap(x1, y1, false, false);
                    uint4v t;
                    t[0] = (unsigned int)r02[0];
                    t[1] = (unsigned int)r13[0];
                    t[2] = (unsigned int)r02[1];
                    t[3] = (unsigned int)r13[1];
                    bf16x8 pa = __builtin_bit_cast(bf16x8, t);
                    // V B-frags: keys (b*2+ks2)*16 + hi*8, cols d = {l31, 32+l31}
                    const int kcb = (b * 2 + ks2) * 2 + hi;
                    bf16x8 v0 = *(const bf16x8*)&Vs[cur][l31 * 64        + ((kcb ^ xr) << 3)];
                    bf16x8 v1 = *(const bf16x8*)&Vs[cur][(32 + l31) * 64 + ((kcb ^ xr) << 3)];
                    o0 = __builtin_amdgcn_mfma_f32_32x32x16_bf16(pa, v0, o0, 0, 0, 0);
                    o1 = __builtin_amdgcn_mfma_f32_32x32x16_bf16(pa, v1, o1, 0, 0, 0);
                }
            }
            __builtin_amdgcn_s_setprio(0);
        }
        // no end-of-iter barrier: next iter's top barrier provides the ordering
    }

    // ---- epilogue: l lives per q-column (lane l31); O rows need redistribution ----
    const float l2 = l_part + __shfl_xor(l_part, 32);   // full denom for q = qw + l31
    const int qw = q0 + wave * 32;
    if (nch == 1) {
        const float inv = 1.0f / l2;
        #pragma unroll
        for (int r = 0; r < 16; ++r) {
            const int qloc = (r & 3) + ((r >> 2) << 3) + (hi << 2);
            const float invq = __shfl(inv, qloc);       // lane qloc holds inv for q=qw+qloc
            const int row = qw + qloc;
            Out[(size_t)row * HD + h * 64 + l31]      = o0[r] * invq;
            Out[(size_t)row * HD + h * 64 + 32 + l31] = o1[r] * invq;
        }
    } else {
        if (hi == 0) atomicAdd(&l_acc[(qw + l31) * 12 + h], l2);
        #pragma unroll
        for (int r = 0; r < 16; ++r) {
            const int qloc = (r & 3) + ((r >> 2) << 3) + (hi << 2);
            const int row = qw + qloc;
            atomicAdd(&Out[(size_t)row * HD + h * 64 + l31],      o0[r]);
            atomicAdd(&Out[(size_t)row * HD + h * 64 + 32 + l31], o1[r]);
        }
    }
}

// ---------------- finalize: divide multi-chunk rows by accumulated l ----------------
__global__ __launch_bounds__(256)
void finalize_kernel(float* __restrict__ Out, const float* __restrict__ l_acc,
                     const int* __restrict__ is_causal_p)
{
    const int causal = (*is_causal_p) != 0;
    const int idx = blockIdx.x * 256 + threadIdx.x;   // 0..786431 (float4 units)
    const int rh = idx >> 4;
    const int d4 = idx & 15;
    const int h = rh % 12;
    const int row = rh / 12;
    const int group = h >> 2;
    const int ntf = 16 << group;                      // k-tiles per segment
    const int qt128 = row >> 7;
    const int qb_t = (qt128 << 1) & (ntf - 1);        // block qb in 64-tiles
    const int nkt = causal ? (qb_t + 2) : ntf;
    if (nkt <= 16) return;                            // single chunk: already normalized
    const float inv = 1.0f / l_acc[rh];
    float4* p = (float4*)Out + (size_t)rh * 16 + d4;
    float4 v = *p;
    v.x *= inv; v.y *= inv; v.z *= inv; v.w *= inv;
    *p = v;
}

extern "C" void kernel_launch(void* const* d_in, const int* in_sizes, int n_in,
                              void* d_out, int out_size, void* d_ws, size_t ws_size,
                              hipStream_t stream) {
    (void)in_sizes; (void)n_in; (void)out_size; (void)ws_size;
    const float* Q = (const float*)d_in[0];
    const float* K = (const float*)d_in[1];
    const float* V = (const float*)d_in[2];
    const int* isc = (const int*)d_in[3];
    float* Out = (float*)d_out;
    ushort_t* Kg   = (ushort_t*)((char*)d_ws + KG_OFF);
    ushort_t* VgT  = (ushort_t*)((char*)d_ws + VGT_OFF);
    float*    lacc = (float*)((char*)d_ws + LACC_OFF);

    preconvert_kernel<<<1536, 256, 0, stream>>>(K, V, Kg, VgT, Out, lacc);
    dilated_attn_kernel<<<1536, 256, 0, stream>>>(Q, Kg, VgT, isc, Out, lacc);
    finalize_kernel<<<3072, 256, 0, stream>>>(Out, lacc, isc);
}